// Round 8
// baseline (91.205 us; speedup 1.0000x reference)
//
#include <hip/hip_runtime.h>
#include <stdint.h>

// ---- problem constants ----
#define DHW         13824      // 24*24*24 spatial positions per (b,c,g) plane
#define NCH         32         // channels C
#define NG          24         // octahedral group order
#define FEATC       72         // NG * N_SEL features per channel
#define KDIM        2304       // NCH * FEATC  (GEMM reduction dim)
#define NHEAD       64
#define TP          8          // spatial positions per block (R7->R8: halved to double occupancy)
#define KPITCH      2312       // feat LDS row pitch in bf16 (+8 pad: rows start 16B & 4-bank apart)
#define TILES_PER_B 1728       // DHW / TP
#define NTILES      3456       // B * TILES_PER_B
#define KSTEPS      72         // KDIM / 32

typedef __attribute__((ext_vector_type(2))) float    f32x2;
typedef __attribute__((ext_vector_type(8))) short    s16x8;
typedef __attribute__((ext_vector_type(4))) float    f32x4;
typedef __attribute__((ext_vector_type(4))) uint32_t u32x4;

// ---- compile-time Cayley table of S4 (matches itertools.permutations order) ----
struct Tables { int cay[NG][NG]; int s1[NG]; int s2[NG]; };

constexpr Tables make_tables() {
    int perms[NG][4] = {};
    int n = 0;
    for (int a = 0; a < 4; ++a)
        for (int b = 0; b < 4; ++b) {
            if (b == a) continue;
            for (int c = 0; c < 4; ++c) {
                if (c == a || c == b) continue;
                int d = 6 - a - b - c;
                perms[n][0] = a; perms[n][1] = b; perms[n][2] = c; perms[n][3] = d;
                ++n;
            }
        }
    int si1 = 0, si2 = 0;
    for (int i = 0; i < NG; ++i) {
        if (perms[i][0] == 1 && perms[i][1] == 0 && perms[i][2] == 2 && perms[i][3] == 3) si1 = i;
        if (perms[i][0] == 1 && perms[i][1] == 2 && perms[i][2] == 3 && perms[i][3] == 0) si2 = i;
    }
    Tables t{};
    for (int p = 0; p < NG; ++p) {
        for (int q = 0; q < NG; ++q) {
            int c0 = perms[p][perms[q][0]];
            int c1 = perms[p][perms[q][1]];
            int c2 = perms[p][perms[q][2]];
            int c3 = perms[p][perms[q][3]];
            int r = 0;
            for (int i = 0; i < NG; ++i)
                if (perms[i][0] == c0 && perms[i][1] == c1 &&
                    perms[i][2] == c2 && perms[i][3] == c3) { r = i; break; }
            t.cay[p][q] = r;
        }
        t.s1[p] = t.cay[p][si1];
        t.s2[p] = t.cay[p][si2];
    }
    return t;
}
constexpr Tables TAB = make_tables();

__device__ __forceinline__ uint32_t f2bf(float f) {   // fp32 -> bf16 (RNE), u16 in low bits
    uint32_t u = __float_as_uint(f);
    u += 0x7fffu + ((u >> 16) & 1u);
    return u >> 16;
}

// ---- kernel 1: W (fp32 64x2304) -> bf16, pre-swizzled into MFMA A-fragment order.
// WbS[((ot*KSTEPS + kk)*64 + lane)*8 + j] = W[ot*16 + (lane&15)][kk*32 + (lane>>4)*8 + j]
__global__ __launch_bounds__(256) void prep_w(const float* __restrict__ W,
                                              unsigned short* __restrict__ WbS) {
    int i = blockIdx.x * 256 + threadIdx.x;
    if (i >= NHEAD * KDIM) return;
    int j  = i & 7;
    int t1 = i >> 3;
    int l  = t1 & 63;
    int t2 = t1 >> 6;
    int kk = t2 % KSTEPS;
    int ot = t2 / KSTEPS;
    int o = ot * 16 + (l & 15);
    int k = kk * 32 + ((l >> 4) << 3) + j;
    WbS[i] = (unsigned short)f2bf(W[o * KDIM + k]);
}

// ---- kernel 2: fused bispectrum + signed-log1p + ReLU + 64x2304 GEMM, 8 positions/block
// 256 threads (4 waves), ONE phase-A row per thread (8 pos x 32 ch = 256 rows).
// R7 lesson: 256-thread blocks get an honest VGPR grant (88) and zero spills; the
// remaining limiter was occupancy (74KB LDS -> 2 blocks/CU -> 2 waves/SIMD, VALUBusy 38%).
// TP=8 halves LDS to 37KB -> 4 blocks/CU = 4 waves/SIMD. Phase-B MFMA uses N=16 with
// cols 8..15 duplicating cols 0..7 (B row = ln&7); stores gated on ln<8. MFMA work
// doubles but MfmaUtil was only 2% -- the VALU/latency side is what we're buying.
__global__ __launch_bounds__(256, 2)
void bispec_fused(
        const float* __restrict__ x,
        const unsigned short* __restrict__ WbS,
        const float* __restrict__ bias,
        float* __restrict__ y)
{
    __shared__ alignas(16) unsigned short featS[TP * KPITCH];   // 36,992 B -> 4 blocks/CU

    const int bid = blockIdx.x;
    // XCD-chunked swizzle: consecutive tiles share an XCD's L2 (3456 % 8 == 0)
    const int swz = (bid & 7) * (NTILES / 8) + (bid >> 3);
    const int bb  = swz / TILES_PER_B;
    const int psp = (swz - bb * TILES_PER_B) * TP;
    const int tid = threadIdx.x;

    // ---------------- phase A: bispectrum features, 1 (c,p) row per thread ----------------
    {
        const int p0 = tid & 7;
        const int c0 = tid >> 3;                         // 0..31
        // 32-bit divergent index vs uniform base -> saddr-form global_load_dword
        const unsigned idx0 = (unsigned)(bb * NCH + c0) * (NG * DHW) + (unsigned)(psp + p0);
        float xf[NG];
        #pragma unroll
        for (int g = 0; g < NG; ++g) xf[g] = x[idx0 + (unsigned)(g * DHW)];

        float tau0[NG];          // s = identity component
        f32x2 tau12[NG];         // (s1, s2) components -> v_pk_fma_f32
        #pragma unroll
        for (int h = 0; h < NG; ++h) { tau0[h] = 0.f; tau12[h] = (f32x2){0.f, 0.f}; }
        #pragma unroll
        for (int g = 0; g < NG; ++g) {
            const float xg = xf[g];
            const float q0 = xg * xg;
            const f32x2 q12 = {xg * xf[TAB.s1[g]], xg * xf[TAB.s2[g]]};
            #pragma unroll
            for (int h = 0; h < NG; ++h) {
                const float v = xf[TAB.cay[g][h]];   // static register index
                tau0[h] = fmaf(q0, v, tau0[h]);
                tau12[h] = __builtin_elementwise_fma((f32x2){v, v}, q12, tau12[h]);
            }
        }
        // relu(sign*log1p(|t|)) == (t>0 ? log(1+t) : 0); pack bf16 pairs
        uint32_t pk[FEATC / 2];
        #pragma unroll
        for (int h = 0; h < NG; h += 2) {
            float f0 = tau0[h]      > 0.f ? __logf(1.f + tau0[h])      : 0.f;
            float f1 = tau12[h][0]  > 0.f ? __logf(1.f + tau12[h][0])  : 0.f;
            float f2 = tau12[h][1]  > 0.f ? __logf(1.f + tau12[h][1])  : 0.f;
            float f3 = tau0[h+1]    > 0.f ? __logf(1.f + tau0[h+1])    : 0.f;
            float f4 = tau12[h+1][0]> 0.f ? __logf(1.f + tau12[h+1][0]): 0.f;
            float f5 = tau12[h+1][1]> 0.f ? __logf(1.f + tau12[h+1][1]): 0.f;
            const int bw = (h >> 1) * 3;
            pk[bw + 0] = f2bf(f0) | (f2bf(f1) << 16);
            pk[bw + 1] = f2bf(f2) | (f2bf(f3) << 16);
            pk[bw + 2] = f2bf(f4) | (f2bf(f5) << 16);
        }
        uint32_t* dst = (uint32_t*)&featS[p0 * KPITCH + c0 * FEATC];  // 16B-aligned
        #pragma unroll
        for (int i = 0; i < FEATC / 2; i += 4) {
            u32x4 v; v[0] = pk[i]; v[1] = pk[i+1]; v[2] = pk[i+2]; v[3] = pk[i+3];
            *(u32x4*)(dst + i) = v;
        }
    }
    __syncthreads();

    // ---------------- phase B: y[64 x 8] = W @ feat via MFMA 16x16x32 bf16 ----------------
    const int wv = tid >> 6;          // wave -> o-tile (16 heads)
    const int l  = tid & 63;
    const int ln = l & 15;            // MFMA col; cols 8..15 duplicate rows 0..7
    const int lh = l >> 4;            // k sub-block

    f32x4 acc0 = {0.f, 0.f, 0.f, 0.f};
    f32x4 acc1 = {0.f, 0.f, 0.f, 0.f};
    const s16x8* wbase = (const s16x8*)WbS + ((size_t)wv * KSTEPS * 64 + l);
    const unsigned short* fb = &featS[(ln & 7) * KPITCH + lh * 8];

    #pragma unroll 4
    for (int kk = 0; kk < KSTEPS; kk += 2) {
        s16x8 a0 = wbase[(size_t)kk * 64];
        s16x8 b0 = *(const s16x8*)(fb + kk * 32);
        acc0 = __builtin_amdgcn_mfma_f32_16x16x32_bf16(a0, b0, acc0, 0, 0, 0);
        s16x8 a1 = wbase[(size_t)(kk + 1) * 64];
        s16x8 b1 = *(const s16x8*)(fb + (kk + 1) * 32);
        acc1 = __builtin_amdgcn_mfma_f32_16x16x32_bf16(a1, b1, acc1, 0, 0, 0);
    }

    // D layout: col = lane&15 (position; only 0..7 real), row = (lane>>4)*4 + j
    if (ln < TP) {
        const size_t ybase = (size_t)bb * NHEAD * DHW + (size_t)(psp + ln);
        #pragma unroll
        for (int j = 0; j < 4; ++j) {
            const int o = wv * 16 + lh * 4 + j;
            y[ybase + (size_t)o * DHW] = acc0[j] + acc1[j] + bias[o];
        }
    }
}

extern "C" void kernel_launch(void* const* d_in, const int* in_sizes, int n_in,
                              void* d_out, int out_size, void* d_ws, size_t ws_size,
                              hipStream_t stream) {
    const float* x    = (const float*)d_in[0];
    const float* W    = (const float*)d_in[1];
    const float* bias = (const float*)d_in[2];
    unsigned short* WbS = (unsigned short*)d_ws;   // 64*2304*2 = 294,912 B

    prep_w<<<dim3((NHEAD * KDIM + 255) / 256), dim3(256), 0, stream>>>(W, WbS);
    bispec_fused<<<dim3(NTILES), dim3(256), 0, stream>>>(x, WbS, bias, (float*)d_out);
}

// Round 9
// 84.732 us; speedup vs baseline: 1.0764x; 1.0764x over previous
//
#include <hip/hip_runtime.h>
#include <stdint.h>

// ---- problem constants ----
#define DHW         13824      // 24*24*24 spatial positions per (b,c,g) plane
#define NCH         32         // channels C
#define NG          24         // octahedral group order
#define FEATC       72         // NG * N_SEL features per channel
#define KDIM        2304       // NCH * FEATC  (GEMM reduction dim)
#define NHEAD       64
#define TP          16         // spatial positions per block
#define CHS         16         // channels per stage (2 stages)
#define KPE         1160       // feat LDS row pitch in bf16 elems (16*72 + 8 pad -> 4-bank skew)
#define TILES_PER_B 864        // DHW / TP
#define NTILES      1728       // B * TILES_PER_B
#define KSTEPS      72         // KDIM / 32
#define KSTG        36         // K-steps per stage
typedef __attribute__((ext_vector_type(2))) float    f32x2;
typedef __attribute__((ext_vector_type(8))) short    s16x8;
typedef __attribute__((ext_vector_type(4))) float    f32x4;
typedef __attribute__((ext_vector_type(4))) uint32_t u32x4;

// ---- compile-time Cayley table of S4 (matches itertools.permutations order) ----
struct Tables { int cay[NG][NG]; int s1[NG]; int s2[NG]; };

constexpr Tables make_tables() {
    int perms[NG][4] = {};
    int n = 0;
    for (int a = 0; a < 4; ++a)
        for (int b = 0; b < 4; ++b) {
            if (b == a) continue;
            for (int c = 0; c < 4; ++c) {
                if (c == a || c == b) continue;
                int d = 6 - a - b - c;
                perms[n][0] = a; perms[n][1] = b; perms[n][2] = c; perms[n][3] = d;
                ++n;
            }
        }
    int si1 = 0, si2 = 0;
    for (int i = 0; i < NG; ++i) {
        if (perms[i][0] == 1 && perms[i][1] == 0 && perms[i][2] == 2 && perms[i][3] == 3) si1 = i;
        if (perms[i][0] == 1 && perms[i][1] == 2 && perms[i][2] == 3 && perms[i][3] == 0) si2 = i;
    }
    Tables t{};
    for (int p = 0; p < NG; ++p) {
        for (int q = 0; q < NG; ++q) {
            int c0 = perms[p][perms[q][0]];
            int c1 = perms[p][perms[q][1]];
            int c2 = perms[p][perms[q][2]];
            int c3 = perms[p][perms[q][3]];
            int r = 0;
            for (int i = 0; i < NG; ++i)
                if (perms[i][0] == c0 && perms[i][1] == c1 &&
                    perms[i][2] == c2 && perms[i][3] == c3) { r = i; break; }
            t.cay[p][q] = r;
        }
        t.s1[p] = t.cay[p][si1];
        t.s2[p] = t.cay[p][si2];
    }
    return t;
}
constexpr Tables TAB = make_tables();

__device__ __forceinline__ uint32_t f2bf(float f) {   // fp32 -> bf16 (RNE), u16 in low bits
    uint32_t u = __float_as_uint(f);
    u += 0x7fffu + ((u >> 16) & 1u);
    return u >> 16;
}

// ---- kernel 1: W (fp32 64x2304) -> bf16, pre-swizzled into MFMA A-fragment order.
// WbS[((ot*KSTEPS + kk)*64 + lane)*8 + j] = W[ot*16 + (lane&15)][kk*32 + (lane>>4)*8 + j]
__global__ __launch_bounds__(256) void prep_w(const float* __restrict__ W,
                                              unsigned short* __restrict__ WbS) {
    int i = blockIdx.x * 256 + threadIdx.x;
    if (i >= NHEAD * KDIM) return;
    int j  = i & 7;
    int t1 = i >> 3;
    int l  = t1 & 63;
    int t2 = t1 >> 6;
    int kk = t2 % KSTEPS;
    int ot = t2 / KSTEPS;
    int o = ot * 16 + (l & 15);
    int k = kk * 32 + ((l >> 4) << 3) + j;
    WbS[i] = (unsigned short)f2bf(W[o * KDIM + k]);
}

// ---- kernel 2: fused bispectrum + signed-log1p + ReLU + 64x2304 GEMM, 16 positions/block
// 256 threads (4 waves), CHANNEL-STAGED: stage s computes features for channels
// 16s..16s+15 (one full row per thread), stores feat[16pos][16ch*72] in 37.1 KB LDS,
// then phase B accumulates that stage's 36 K-steps into persistent registers.
// Rationale (R7/R8 post-mortems): 256-thread blocks get an honest VGPR grant (84-88,
// no spills); TP=16 full-K LDS (74 KB) capped occupancy at 2 blocks/CU (R7, 85.5us);
// TP=8 (37 KB) raised occupancy but doubled MFMA + L2 + bank-conflict work via
// column duplication (R8, 91.2us). Channel-staging gets 37 KB LDS AND zero duplicated
// MFMA: K is accumulated across stages in registers, N=16 real positions.
__global__ __launch_bounds__(256, 2)
void bispec_fused(
        const float* __restrict__ x,
        const unsigned short* __restrict__ WbS,
        const float* __restrict__ bias,
        float* __restrict__ y)
{
    __shared__ alignas(16) unsigned short featS[TP * KPE];   // 37,120 B -> 4 blocks/CU

    const int bid = blockIdx.x;
    // XCD-chunked swizzle: consecutive tiles share an XCD's L2 (1728 % 8 == 0)
    const int swz = (bid & 7) * (NTILES / 8) + (bid >> 3);
    const int bb  = swz / TILES_PER_B;
    const int psp = (swz - bb * TILES_PER_B) * TP;
    const int tid = threadIdx.x;

    const int p0 = tid & 15;          // position within tile (phase A)
    const int cl = tid >> 4;          // local channel 0..15 (phase A)
    const int wv = tid >> 6;          // wave -> o-tile (16 heads)  (phase B)
    const int l  = tid & 63;
    const int ln = l & 15;            // position col (phase B)
    const int lh = l >> 4;            // k sub-block (phase B)

    f32x4 acc0 = {0.f, 0.f, 0.f, 0.f};
    f32x4 acc1 = {0.f, 0.f, 0.f, 0.f};

    #pragma unroll 1                  // stages strictly sequential: no live-range merge
    for (int stage = 0; stage < 2; ++stage) {
        // ---------------- phase A: one full (c,p) row per thread ----------------
        {
            const int c0 = stage * CHS + cl;
            // 32-bit divergent index vs uniform base -> saddr-form global_load_dword
            const unsigned idx0 = (unsigned)(bb * NCH + c0) * (NG * DHW) + (unsigned)(psp + p0);
            float xf[NG];
            #pragma unroll
            for (int g = 0; g < NG; ++g) xf[g] = x[idx0 + (unsigned)(g * DHW)];

            float tau0[NG];          // s = identity component
            f32x2 tau12[NG];         // (s1, s2) components -> v_pk_fma_f32
            #pragma unroll
            for (int h = 0; h < NG; ++h) { tau0[h] = 0.f; tau12[h] = (f32x2){0.f, 0.f}; }
            #pragma unroll
            for (int g = 0; g < NG; ++g) {
                const float xg = xf[g];
                const float q0 = xg * xg;
                const f32x2 q12 = {xg * xf[TAB.s1[g]], xg * xf[TAB.s2[g]]};
                #pragma unroll
                for (int h = 0; h < NG; ++h) {
                    const float v = xf[TAB.cay[g][h]];   // static register index
                    tau0[h] = fmaf(q0, v, tau0[h]);
                    tau12[h] = __builtin_elementwise_fma((f32x2){v, v}, q12, tau12[h]);
                }
            }
            // relu(sign*log1p(|t|)) == (t>0 ? log(1+t) : 0); pack bf16 pairs
            uint32_t pk[FEATC / 2];
            #pragma unroll
            for (int h = 0; h < NG; h += 2) {
                float f0 = tau0[h]      > 0.f ? __logf(1.f + tau0[h])      : 0.f;
                float f1 = tau12[h][0]  > 0.f ? __logf(1.f + tau12[h][0])  : 0.f;
                float f2 = tau12[h][1]  > 0.f ? __logf(1.f + tau12[h][1])  : 0.f;
                float f3 = tau0[h+1]    > 0.f ? __logf(1.f + tau0[h+1])    : 0.f;
                float f4 = tau12[h+1][0]> 0.f ? __logf(1.f + tau12[h+1][0]): 0.f;
                float f5 = tau12[h+1][1]> 0.f ? __logf(1.f + tau12[h+1][1]): 0.f;
                const int bw = (h >> 1) * 3;
                pk[bw + 0] = f2bf(f0) | (f2bf(f1) << 16);
                pk[bw + 1] = f2bf(f2) | (f2bf(f3) << 16);
                pk[bw + 2] = f2bf(f4) | (f2bf(f5) << 16);
            }
            // row start: p0*2320B (16B-aligned), + cl*144B (16B-aligned)
            uint32_t* dst = (uint32_t*)&featS[p0 * KPE + cl * FEATC];
            #pragma unroll
            for (int i = 0; i < FEATC / 2; i += 4) {
                u32x4 v; v[0] = pk[i]; v[1] = pk[i+1]; v[2] = pk[i+2]; v[3] = pk[i+3];
                *(u32x4*)(dst + i) = v;
            }
        }
        __syncthreads();

        // -------- phase B: accumulate this stage's 36 K-steps (16 real positions) --------
        {
            const s16x8* wbase = (const s16x8*)WbS
                               + ((size_t)(wv * KSTEPS + stage * KSTG) * 64 + l);
            // lane rows: ln*2320B -> dword stride 580 = 4 banks apart -> 2-way (free)
            const unsigned short* fb = &featS[ln * KPE + lh * 8];

            #pragma unroll 4
            for (int kk = 0; kk < KSTG; kk += 2) {
                s16x8 a0 = wbase[(size_t)kk * 64];
                s16x8 b0 = *(const s16x8*)(fb + kk * 32);
                acc0 = __builtin_amdgcn_mfma_f32_16x16x32_bf16(a0, b0, acc0, 0, 0, 0);
                s16x8 a1 = wbase[(size_t)(kk + 1) * 64];
                s16x8 b1 = *(const s16x8*)(fb + (kk + 1) * 32);
                acc1 = __builtin_amdgcn_mfma_f32_16x16x32_bf16(a1, b1, acc1, 0, 0, 0);
            }
        }
        __syncthreads();   // stage 0: protect LDS before overwrite; stage 1: cheap
    }

    // D layout: col = lane&15 (position), row = (lane>>4)*4 + j (head within o-tile)
    const size_t ybase = (size_t)bb * NHEAD * DHW + (size_t)(psp + ln);
    #pragma unroll
    for (int j = 0; j < 4; ++j) {
        const int o = wv * 16 + lh * 4 + j;
        y[ybase + (size_t)o * DHW] = acc0[j] + acc1[j] + bias[o];
    }
}

extern "C" void kernel_launch(void* const* d_in, const int* in_sizes, int n_in,
                              void* d_out, int out_size, void* d_ws, size_t ws_size,
                              hipStream_t stream) {
    const float* x    = (const float*)d_in[0];
    const float* W    = (const float*)d_in[1];
    const float* bias = (const float*)d_in[2];
    unsigned short* WbS = (unsigned short*)d_ws;   // 64*2304*2 = 294,912 B

    prep_w<<<dim3((NHEAD * KDIM + 255) / 256), dim3(256), 0, stream>>>(W, WbS);
    bispec_fused<<<dim3(NTILES), dim3(256), 0, stream>>>(x, WbS, bias, (float*)d_out);
}

// Round 11
// 74.494 us; speedup vs baseline: 1.2243x; 1.1374x over previous
//
#include <hip/hip_runtime.h>
#include <stdint.h>

// ---- problem constants ----
#define DHW         13824      // 24*24*24 spatial positions per (b,c,g) plane
#define NCH         32         // channels C
#define NG          24         // octahedral group order
#define FEATC       72         // NG * N_SEL features per channel
#define KDIM        2304       // NCH * FEATC  (GEMM reduction dim)
#define NHEAD       64
#define TP          16         // spatial positions per block
#define CHS         16         // channels per stage (2 stages)
#define KPE         1160       // feat LDS row pitch in bf16 elems (16*72 + 8 pad)
#define TILES_PER_B 864        // DHW / TP
#define NTILES      1728       // B * TILES_PER_B
#define KSTEPS      72         // KDIM / 32
#define KSTG        36         // K-steps per stage
#define OUTN        1769472    // B * NHEAD * DHW  (output floats)
#define WS_WBS      294912     // bytes for swizzled W
#define WS_NEED     (WS_WBS + 2u * OUTN * 4u)   // + two partial-sum planes

typedef __attribute__((ext_vector_type(2))) float    f32x2;
typedef __attribute__((ext_vector_type(8))) short    s16x8;
typedef __attribute__((ext_vector_type(4))) float    f32x4;
typedef __attribute__((ext_vector_type(4))) uint32_t u32x4;

// ---- compile-time Cayley table of S4 (matches itertools.permutations order) ----
struct Tables { int cay[NG][NG]; int s1[NG]; int s2[NG]; };

constexpr Tables make_tables() {
    int perms[NG][4] = {};
    int n = 0;
    for (int a = 0; a < 4; ++a)
        for (int b = 0; b < 4; ++b) {
            if (b == a) continue;
            for (int c = 0; c < 4; ++c) {
                if (c == a || c == b) continue;
                int d = 6 - a - b - c;
                perms[n][0] = a; perms[n][1] = b; perms[n][2] = c; perms[n][3] = d;
                ++n;
            }
        }
    int si1 = 0, si2 = 0;
    for (int i = 0; i < NG; ++i) {
        if (perms[i][0] == 1 && perms[i][1] == 0 && perms[i][2] == 2 && perms[i][3] == 3) si1 = i;
        if (perms[i][0] == 1 && perms[i][1] == 2 && perms[i][2] == 3 && perms[i][3] == 0) si2 = i;
    }
    Tables t{};
    for (int p = 0; p < NG; ++p) {
        for (int q = 0; q < NG; ++q) {
            int c0 = perms[p][perms[q][0]];
            int c1 = perms[p][perms[q][1]];
            int c2 = perms[p][perms[q][2]];
            int c3 = perms[p][perms[q][3]];
            int r = 0;
            for (int i = 0; i < NG; ++i)
                if (perms[i][0] == c0 && perms[i][1] == c1 &&
                    perms[i][2] == c2 && perms[i][3] == c3) { r = i; break; }
            t.cay[p][q] = r;
        }
        t.s1[p] = t.cay[p][si1];
        t.s2[p] = t.cay[p][si2];
    }
    return t;
}
constexpr Tables TAB = make_tables();

__device__ __forceinline__ uint32_t f2bf(float f) {   // fp32 -> bf16 (RNE), u16 in low bits
    uint32_t u = __float_as_uint(f);
    u += 0x7fffu + ((u >> 16) & 1u);
    return u >> 16;
}

// ---- kernel 1: W (fp32 64x2304) -> bf16*ln2, pre-swizzled into MFMA A-fragment order.
// ln2 folded in so phase A can use log2 instead of log1p (saves a v_mul per feature).
__global__ __launch_bounds__(256) void prep_w(const float* __restrict__ W,
                                              unsigned short* __restrict__ WbS) {
    int i = blockIdx.x * 256 + threadIdx.x;
    if (i >= NHEAD * KDIM) return;
    int j  = i & 7;
    int t1 = i >> 3;
    int l  = t1 & 63;
    int t2 = t1 >> 6;
    int kk = t2 % KSTEPS;
    int ot = t2 / KSTEPS;
    int o = ot * 16 + (l & 15);
    int k = kk * 32 + ((l >> 4) << 3) + j;
    WbS[i] = (unsigned short)f2bf(W[o * KDIM + k] * 0.69314718055994531f);
}

// ---- kernel 3: y = partial0 + partial1 + bias (split path only) ----
__global__ __launch_bounds__(256) void reduce_y(const float* __restrict__ part,
                                                const float* __restrict__ bias,
                                                float* __restrict__ y) {
    const int i4 = blockIdx.x * 256 + threadIdx.x;      // float4 index, OUTN%1024==0
    const f32x4 v0 = ((const f32x4*)part)[i4];
    const f32x4 v1 = ((const f32x4*)(part + OUTN))[i4];
    const float b  = bias[((i4 * 4) / DHW) & (NHEAD - 1)];
    f32x4 r = v0 + v1;
    r[0] += b; r[1] += b; r[2] += b; r[3] += b;
    ((f32x4*)y)[i4] = r;
}

// ---- kernel 2: fused bispectrum + log-feature + 64-head GEMM, 16 positions/block.
// 256 threads (4 waves). SPLIT=1: each block does ONE channel-stage (grid 3456),
// partial sums to ws (R9 lesson: grid 1728 = 1.7 occupancy fills -> 20% occupancy).
// SPLIT=0: fused 2-stage fallback when ws is too small.
// R10 post-mortem: v_cvt_pk_bf16_f32 produced O(|y|) errors (suspected lo/hi operand
// order mismatch) -> BANNED; back to R9's proven manual-RNE f2bf pack. Kept the safe
// tail opts: feature = log2(1+max(tau,0)) with ln2 folded into W (v_max replaces
// cmp+sel, no per-feature v_mul).
template<int SPLIT>
__global__ __launch_bounds__(256, 2)
void bispec_fused(
        const float* __restrict__ x,
        const unsigned short* __restrict__ WbS,
        const float* __restrict__ bias,
        float* __restrict__ out)          // SPLIT ? partial planes : final y
{
    __shared__ alignas(16) unsigned short featS[TP * KPE];   // 37,120 B -> 4 blocks/CU

    const int bid = blockIdx.x;
    const int NB  = SPLIT ? NTILES * 2 : NTILES;
    // XCD-chunked swizzle (NB % 8 == 0); bijection bid -> (tile, stage)
    const int swz   = (bid & 7) * (NB / 8) + (bid >> 3);
    const int tile  = SPLIT ? (swz % NTILES) : swz;
    const int sbeg  = SPLIT ? (swz / NTILES) : 0;
    const int send  = SPLIT ? sbeg + 1 : 2;
    const int bb  = tile / TILES_PER_B;
    const int psp = (tile - bb * TILES_PER_B) * TP;
    const int tid = threadIdx.x;

    const int p0 = tid & 15;          // position within tile (phase A)
    const int cl = tid >> 4;          // local channel 0..15 (phase A)
    const int wv = tid >> 6;          // wave -> o-tile (16 heads)  (phase B)
    const int l  = tid & 63;
    const int ln = l & 15;            // position col (phase B)
    const int lh = l >> 4;            // k sub-block (phase B)

    f32x4 acc0 = {0.f, 0.f, 0.f, 0.f};
    f32x4 acc1 = {0.f, 0.f, 0.f, 0.f};

    #pragma unroll 1                  // stages strictly sequential: no live-range merge
    for (int stage = sbeg; stage < send; ++stage) {
        // ---------------- phase A: one full (c,p) row per thread ----------------
        {
            const int c0 = stage * CHS + cl;
            // 32-bit divergent index vs uniform base -> saddr-form global_load_dword
            const unsigned idx0 = (unsigned)(bb * NCH + c0) * (NG * DHW) + (unsigned)(psp + p0);
            float xf[NG];
            #pragma unroll
            for (int g = 0; g < NG; ++g) xf[g] = x[idx0 + (unsigned)(g * DHW)];

            float tau0[NG];          // s = identity component
            f32x2 tau12[NG];         // (s1, s2) components -> v_pk_fma_f32
            #pragma unroll
            for (int h = 0; h < NG; ++h) { tau0[h] = 0.f; tau12[h] = (f32x2){0.f, 0.f}; }
            #pragma unroll
            for (int g = 0; g < NG; ++g) {
                const float xg = xf[g];
                const float q0 = xg * xg;
                const f32x2 q12 = {xg * xf[TAB.s1[g]], xg * xf[TAB.s2[g]]};
                #pragma unroll
                for (int h = 0; h < NG; ++h) {
                    const float v = xf[TAB.cay[g][h]];   // static register index
                    tau0[h] = fmaf(q0, v, tau0[h]);
                    tau12[h] = __builtin_elementwise_fma((f32x2){v, v}, q12, tau12[h]);
                }
            }
            // feature = log2(1 + max(tau,0))  [ln2 folded into W; log2(1)=0 exact]
            uint32_t pk[FEATC / 2];
            #pragma unroll
            for (int h = 0; h < NG; h += 2) {
                float f0 = __log2f(1.f + fmaxf(tau0[h],       0.f));
                float f1 = __log2f(1.f + fmaxf(tau12[h][0],   0.f));
                float f2 = __log2f(1.f + fmaxf(tau12[h][1],   0.f));
                float f3 = __log2f(1.f + fmaxf(tau0[h+1],     0.f));
                float f4 = __log2f(1.f + fmaxf(tau12[h+1][0], 0.f));
                float f5 = __log2f(1.f + fmaxf(tau12[h+1][1], 0.f));
                const int bw = (h >> 1) * 3;
                pk[bw + 0] = f2bf(f0) | (f2bf(f1) << 16);
                pk[bw + 1] = f2bf(f2) | (f2bf(f3) << 16);
                pk[bw + 2] = f2bf(f4) | (f2bf(f5) << 16);
            }
            // row start: p0*2320B (16B-aligned), + cl*144B (16B-aligned)
            uint32_t* dst = (uint32_t*)&featS[p0 * KPE + cl * FEATC];
            #pragma unroll
            for (int i = 0; i < FEATC / 2; i += 4) {
                u32x4 v; v[0] = pk[i]; v[1] = pk[i+1]; v[2] = pk[i+2]; v[3] = pk[i+3];
                *(u32x4*)(dst + i) = v;
            }
        }
        __syncthreads();

        // -------- phase B: accumulate this stage's 36 K-steps (16 real positions) --------
        {
            const s16x8* wbase = (const s16x8*)WbS
                               + ((size_t)(wv * KSTEPS + stage * KSTG) * 64 + l);
            // lane rows: ln*2320B -> dword stride 580 = 4 banks apart -> 2-way (free)
            const unsigned short* fb = &featS[ln * KPE + lh * 8];

            #pragma unroll 4
            for (int kk = 0; kk < KSTG; kk += 2) {
                s16x8 a0 = wbase[(size_t)kk * 64];
                s16x8 b0 = *(const s16x8*)(fb + kk * 32);
                acc0 = __builtin_amdgcn_mfma_f32_16x16x32_bf16(a0, b0, acc0, 0, 0, 0);
                s16x8 a1 = wbase[(size_t)(kk + 1) * 64];
                s16x8 b1 = *(const s16x8*)(fb + (kk + 1) * 32);
                acc1 = __builtin_amdgcn_mfma_f32_16x16x32_bf16(a1, b1, acc1, 0, 0, 0);
            }
        }
        if (!SPLIT) __syncthreads();   // protect LDS before stage-1 overwrite
    }

    // D layout: col = lane&15 (position), row = (lane>>4)*4 + j (head within o-tile)
    const size_t obase = (SPLIT ? (size_t)sbeg * OUTN : 0)
                       + (size_t)bb * NHEAD * DHW + (size_t)(psp + ln);
    #pragma unroll
    for (int j = 0; j < 4; ++j) {
        const int o = wv * 16 + lh * 4 + j;
        const float bv = SPLIT ? 0.f : bias[o];
        out[obase + (size_t)o * DHW] = acc0[j] + acc1[j] + bv;
    }
}

extern "C" void kernel_launch(void* const* d_in, const int* in_sizes, int n_in,
                              void* d_out, int out_size, void* d_ws, size_t ws_size,
                              hipStream_t stream) {
    const float* x    = (const float*)d_in[0];
    const float* W    = (const float*)d_in[1];
    const float* bias = (const float*)d_in[2];
    unsigned short* WbS = (unsigned short*)d_ws;            // 294,912 B
    float* part = (float*)((char*)d_ws + WS_WBS);           // 2 x OUTN floats

    prep_w<<<dim3((NHEAD * KDIM + 255) / 256), dim3(256), 0, stream>>>(W, WbS);
    if (ws_size >= (size_t)WS_NEED) {
        bispec_fused<1><<<dim3(NTILES * 2), dim3(256), 0, stream>>>(x, WbS, bias, part);
        reduce_y<<<dim3(OUTN / 4 / 256), dim3(256), 0, stream>>>(part, bias, (float*)d_out);
    } else {
        bispec_fused<0><<<dim3(NTILES), dim3(256), 0, stream>>>(x, WbS, bias, (float*)d_out);
    }
}